// Round 2
// baseline (420.484 us; speedup 1.0000x reference)
//
#include <hip/hip_runtime.h>

// Fused spatio-temporal GCN, MI355X (gfx950), fp32 (no fp32 MFMA -> vector ALU).
// T=128, N=256, H=4, EMB=16, IN_DIMS=5, HID=64.
//
// R2: all adjacency reads now stream coalesced through LDS:
//   - 64-thread (1-wave) blocks, each owns 64 output rows of one (t,h)/(n,h) slice
//   - async global_load_lds (16B/lane) with PRE-SWIZZLED global source so the
//     linear LDS write lands data XOR-swizzled; row-per-lane ds_read_b128 then
//     hits the 8-way b128 bank floor instead of 32-way
//   - K2 stages adj_s with NT (aux=2) to keep adj_t (read by K1) LLC-resident for K3
//   - K3 MLP uses fast tanh via v_exp/v_rcp

#define T_DIM 128
#define N_DIM 256
#define H_DIM 4

typedef const __attribute__((address_space(1))) void* gas_ptr;
typedef __attribute__((address_space(3))) void* las_ptr;

// Stage a [64 rows][64 floats] tile (16 KB) from global (row stride rs bytes,
// starting at byte column koff) into LDS. LDS dest walks linearly; the global
// source is pre-swizzled with the same involution the reader applies, so
// LDS[p] holds A[p ^ (((p>>8)&15)<<4)].
__device__ __forceinline__ void stage64x64(const char* __restrict__ gslice, int rs, int koff,
                                           float* tile, int lane) {
#pragma unroll
  for (int i = 0; i < 16; ++i) {
    int p = (i << 10) + (lane << 4);
    int ps = p ^ (((p >> 8) & 15) << 4);
    const char* src = gslice + (ps >> 8) * rs + koff + (ps & 255);
    __builtin_amdgcn_global_load_lds((gas_ptr)src, (las_ptr)(tile + (i << 8)), 16, 0, 0);
  }
}
__device__ __forceinline__ void stage64x64_nt(const char* __restrict__ gslice, int rs, int koff,
                                              float* tile, int lane) {
#pragma unroll
  for (int i = 0; i < 16; ++i) {
    int p = (i << 10) + (lane << 4);
    int ps = p ^ (((p >> 8) & 15) << 4);
    const char* src = gslice + (ps >> 8) * rs + koff + (ps & 255);
    __builtin_amdgcn_global_load_lds((gas_ptr)src, (las_ptr)(tile + (i << 8)), 16, 0, 2);
  }
}

// Read 4 consecutive floats of row `row` at float-index kk (multiple of 4).
__device__ __forceinline__ float4 tile_read(const float* tile, int row, int kk) {
  int byt = (row << 8) + (kk << 2);
  byt ^= (row & 15) << 4;
  return *(const float4*)((const char*)tile + byt);
}

// ---------------- K1: l1t -> B_pack[t][h][n][8..23]; h==0 also fills spa cols 0..4 ----
__global__ __launch_bounds__(64) void k1_l1t(
    const float* __restrict__ graph, const float* __restrict__ adj_t,
    const float* __restrict__ W_t1, const float* __restrict__ a_t1,
    float* __restrict__ B_pack)
{
    __shared__ __align__(16) float tile[4096];
    const int n = blockIdx.x, h = blockIdx.y, rb = blockIdx.z;
    const int lane = threadIdx.x;
    const int t = rb * 64 + lane;

    const char* aslice = (const char*)(adj_t + ((size_t)(n * H_DIM + h) * T_DIM + rb * 64) * T_DIM);

    float acc[5] = {0.f, 0.f, 0.f, 0.f, 0.f};
    for (int kc = 0; kc < 2; ++kc) {
        stage64x64(aslice, T_DIM * 4, kc * 256, tile, lane);
        __syncthreads();
        for (int kk = 0; kk < 64; kk += 4) {
            const float4 a4 = tile_read(tile, lane, kk);
            const float av[4] = {a4.x, a4.y, a4.z, a4.w};
#pragma unroll
            for (int j = 0; j < 4; ++j) {
                const int k = kc * 64 + kk + j;
                const float* b = graph + (k * N_DIM + n) * 6 + 1;  // wave-uniform
                const float a = av[j];
#pragma unroll
                for (int d = 0; d < 5; ++d) acc[d] = fmaf(a, b[d], acc[d]);
            }
        }
        __syncthreads();
    }

    const float alpha = a_t1[0];
    float v[16];
#pragma unroll
    for (int e = 0; e < 16; ++e) {
        float s = 0.f;
#pragma unroll
        for (int d = 0; d < 5; ++d) s = fmaf(acc[d], W_t1[e * 5 + d], s);
        v[e] = (s >= 0.f) ? s : alpha * s;
    }
    float* dst = B_pack + ((size_t)(t * H_DIM + h) * N_DIM + n) * 24 + 8;
#pragma unroll
    for (int q = 0; q < 4; ++q)
        *(float4*)(dst + 4 * q) = make_float4(v[4*q], v[4*q+1], v[4*q+2], v[4*q+3]);

    if (h == 0) {
        const float* g = graph + (t * N_DIM + n) * 6 + 1;
        float s0 = g[0], s1 = g[1], s2 = g[2], s3 = g[3], s4 = g[4];
#pragma unroll
        for (int hh = 0; hh < H_DIM; ++hh) {
            float* sd = B_pack + ((size_t)(t * H_DIM + hh) * N_DIM + n) * 24;
            sd[0] = s0; sd[1] = s1; sd[2] = s2; sd[3] = s3; sd[4] = s4;
        }
    }
}

// ---------------- K2: C = adj_s[t,h] @ B_pack -> l1s (B_pack2) + Ht (Ht_f) ----------
__global__ __launch_bounds__(64) void k2_l1s_ht(
    const float* __restrict__ adj_s, const float* __restrict__ B_pack,
    const float* __restrict__ W_s1, const float* __restrict__ a_s1,
    const float* __restrict__ W_t2, const float* __restrict__ a_t2,
    float* __restrict__ B_pack2, float* __restrict__ Ht_f)
{
    __shared__ __align__(16) float tile[4096];
    const int t = blockIdx.x, h = blockIdx.y, q = blockIdx.z;
    const int lane = threadIdx.x;
    const int n = q * 64 + lane;

    const char* aslice = (const char*)(adj_s + ((size_t)(t * H_DIM + h) * N_DIM + q * 64) * N_DIM);
    const float* bp = B_pack + (size_t)(t * H_DIM + h) * (N_DIM * 24);

    float acc[21];
#pragma unroll
    for (int i = 0; i < 21; ++i) acc[i] = 0.f;

    for (int kc = 0; kc < 4; ++kc) {
        stage64x64_nt(aslice, N_DIM * 4, kc * 256, tile, lane);
        __syncthreads();
        for (int kk = 0; kk < 64; kk += 4) {
            const float4 a4 = tile_read(tile, lane, kk);
            const float av[4] = {a4.x, a4.y, a4.z, a4.w};
#pragma unroll
            for (int j = 0; j < 4; ++j) {
                const float* b = bp + (kc * 64 + kk + j) * 24;  // wave-uniform
                const float a = av[j];
                const float4 b0 = *(const float4*)(b);
                const float  b4 = b[4];
                const float4 c0 = *(const float4*)(b + 8);
                const float4 c1 = *(const float4*)(b + 12);
                const float4 c2 = *(const float4*)(b + 16);
                const float4 c3 = *(const float4*)(b + 20);
                acc[0] = fmaf(a, b0.x, acc[0]);  acc[1] = fmaf(a, b0.y, acc[1]);
                acc[2] = fmaf(a, b0.z, acc[2]);  acc[3] = fmaf(a, b0.w, acc[3]);
                acc[4] = fmaf(a, b4,   acc[4]);
                acc[5]  = fmaf(a, c0.x, acc[5]);  acc[6]  = fmaf(a, c0.y, acc[6]);
                acc[7]  = fmaf(a, c0.z, acc[7]);  acc[8]  = fmaf(a, c0.w, acc[8]);
                acc[9]  = fmaf(a, c1.x, acc[9]);  acc[10] = fmaf(a, c1.y, acc[10]);
                acc[11] = fmaf(a, c1.z, acc[11]); acc[12] = fmaf(a, c1.w, acc[12]);
                acc[13] = fmaf(a, c2.x, acc[13]); acc[14] = fmaf(a, c2.y, acc[14]);
                acc[15] = fmaf(a, c2.z, acc[15]); acc[16] = fmaf(a, c2.w, acc[16]);
                acc[17] = fmaf(a, c3.x, acc[17]); acc[18] = fmaf(a, c3.y, acc[18]);
                acc[19] = fmaf(a, c3.z, acc[19]); acc[20] = fmaf(a, c3.w, acc[20]);
            }
        }
        __syncthreads();
    }

    // l1s = prelu(C_spa @ W_s1^T) -> B_pack2[n][h][t][e]
    {
        const float alpha = a_s1[0];
        float v[16];
#pragma unroll
        for (int e = 0; e < 16; ++e) {
            float s = 0.f;
#pragma unroll
            for (int d = 0; d < 5; ++d) s = fmaf(acc[d], W_s1[e * 5 + d], s);
            v[e] = (s >= 0.f) ? s : alpha * s;
        }
        float* dst = B_pack2 + ((size_t)(n * H_DIM + h) * T_DIM + t) * 16;
#pragma unroll
        for (int qq = 0; qq < 4; ++qq)
            *(float4*)(dst + 4 * qq) = make_float4(v[4*qq], v[4*qq+1], v[4*qq+2], v[4*qq+3]);
    }
    // Ht = prelu(C_l1t @ W_t2^T) -> Ht_f[n][t][h][e]
    {
        const float alpha = a_t2[0];
        float v[16];
#pragma unroll
        for (int e = 0; e < 16; ++e) {
            float s = 0.f;
#pragma unroll
            for (int e2 = 0; e2 < 16; ++e2) s = fmaf(acc[5 + e2], W_t2[e * 16 + e2], s);
            v[e] = (s >= 0.f) ? s : alpha * s;
        }
        float* dst = Ht_f + ((size_t)(n * T_DIM + t) * H_DIM + h) * 16;
#pragma unroll
        for (int qq = 0; qq < 4; ++qq)
            *(float4*)(dst + 4 * qq) = make_float4(v[4*qq], v[4*qq+1], v[4*qq+2], v[4*qq+3]);
    }
}

// ---------------- K3: Hs + fused MLP/softmax/blend -> out[n][t][h][:] ----------------
__global__ __launch_bounds__(64) void k3_hs_mlp(
    const float* __restrict__ adj_t, const float* __restrict__ B_pack2,
    const float* __restrict__ W_s2, const float* __restrict__ a_s2,
    const float* __restrict__ Ht_f,
    const float* __restrict__ Wm1, const float* __restrict__ bm1,
    const float* __restrict__ Wm2, const float* __restrict__ bm2,
    float* __restrict__ out)
{
    __shared__ __align__(16) float tile[4096];
    const int n = blockIdx.x, h = blockIdx.y, rb = blockIdx.z;
    const int lane = threadIdx.x;
    const int t = rb * 64 + lane;

    const char* aslice = (const char*)(adj_t + ((size_t)(n * H_DIM + h) * T_DIM + rb * 64) * T_DIM);
    const float* bp = B_pack2 + (size_t)(n * H_DIM + h) * (T_DIM * 16);

    float acc[16];
#pragma unroll
    for (int i = 0; i < 16; ++i) acc[i] = 0.f;

    for (int kc = 0; kc < 2; ++kc) {
        stage64x64(aslice, T_DIM * 4, kc * 256, tile, lane);
        __syncthreads();
        for (int kk = 0; kk < 64; kk += 4) {
            const float4 a4 = tile_read(tile, lane, kk);
            const float av[4] = {a4.x, a4.y, a4.z, a4.w};
#pragma unroll
            for (int j = 0; j < 4; ++j) {
                const float* b = bp + (kc * 64 + kk + j) * 16;  // wave-uniform
                const float a = av[j];
                const float4 c0 = *(const float4*)(b);
                const float4 c1 = *(const float4*)(b + 4);
                const float4 c2 = *(const float4*)(b + 8);
                const float4 c3 = *(const float4*)(b + 12);
                acc[0]  = fmaf(a, c0.x, acc[0]);  acc[1]  = fmaf(a, c0.y, acc[1]);
                acc[2]  = fmaf(a, c0.z, acc[2]);  acc[3]  = fmaf(a, c0.w, acc[3]);
                acc[4]  = fmaf(a, c1.x, acc[4]);  acc[5]  = fmaf(a, c1.y, acc[5]);
                acc[6]  = fmaf(a, c1.z, acc[6]);  acc[7]  = fmaf(a, c1.w, acc[7]);
                acc[8]  = fmaf(a, c2.x, acc[8]);  acc[9]  = fmaf(a, c2.y, acc[9]);
                acc[10] = fmaf(a, c2.z, acc[10]); acc[11] = fmaf(a, c2.w, acc[11]);
                acc[12] = fmaf(a, c3.x, acc[12]); acc[13] = fmaf(a, c3.y, acc[13]);
                acc[14] = fmaf(a, c3.z, acc[14]); acc[15] = fmaf(a, c3.w, acc[15]);
            }
        }
        __syncthreads();
    }

    // Hs = prelu(acc @ W_s2^T)
    float hs[16], ht[16];
    {
        const float alpha = a_s2[0];
#pragma unroll
        for (int e = 0; e < 16; ++e) {
            float s = 0.f;
#pragma unroll
            for (int e2 = 0; e2 < 16; ++e2) s = fmaf(acc[e2], W_s2[e * 16 + e2], s);
            hs[e] = (s >= 0.f) ? s : alpha * s;
        }
    }
    const size_t rowbase = ((size_t)(n * T_DIM + t) * H_DIM + h) * 16;
    {
        const float* htp = Ht_f + rowbase;
#pragma unroll
        for (int qq = 0; qq < 4; ++qq) {
            const float4 v = *(const float4*)(htp + 4 * qq);
            ht[4*qq] = v.x; ht[4*qq+1] = v.y; ht[4*qq+2] = v.z; ht[4*qq+3] = v.w;
        }
    }

    // MLP: h = tanh(comb @ Wm1^T + bm1); z = h @ Wm2^T + bm2; 2-way softmax == sigmoid
    float z0 = bm2[0], z1 = bm2[1];
    for (int j = 0; j < 64; ++j) {
        float s = bm1[j];
        const float* w = Wm1 + j * 32;  // wave-uniform
#pragma unroll
        for (int i = 0; i < 16; ++i) s = fmaf(hs[i], w[i], s);
#pragma unroll
        for (int i = 0; i < 16; ++i) s = fmaf(ht[i], w[16 + i], s);
        // fast tanh: 1 - 2/(1+e^{2s}) ; inf-safe at both ends
        const float e = __expf(2.0f * s);
        const float hj = 1.0f - 2.0f * __builtin_amdgcn_rcpf(1.0f + e);
        z0 = fmaf(hj, Wm2[j], z0);
        z1 = fmaf(hj, Wm2[64 + j], z1);
    }
    const float w0 = __builtin_amdgcn_rcpf(1.0f + __expf(z1 - z0));
    const float w1 = 1.0f - w0;

    float* op = out + rowbase;
#pragma unroll
    for (int qq = 0; qq < 4; ++qq) {
        *(float4*)(op + 4 * qq) = make_float4(
            fmaf(w0, hs[4*qq+0], w1 * ht[4*qq+0]),
            fmaf(w0, hs[4*qq+1], w1 * ht[4*qq+1]),
            fmaf(w0, hs[4*qq+2], w1 * ht[4*qq+2]),
            fmaf(w0, hs[4*qq+3], w1 * ht[4*qq+3]));
    }
}

extern "C" void kernel_launch(void* const* d_in, const int* in_sizes, int n_in,
                              void* d_out, int out_size, void* d_ws, size_t ws_size,
                              hipStream_t stream)
{
    const float* graph = (const float*)d_in[0];
    const float* adj_s = (const float*)d_in[1];
    const float* adj_t = (const float*)d_in[2];
    const float* W_s1  = (const float*)d_in[3];
    const float* a_s1  = (const float*)d_in[4];
    const float* W_s2  = (const float*)d_in[5];
    const float* a_s2  = (const float*)d_in[6];
    const float* W_t1  = (const float*)d_in[7];
    const float* a_t1  = (const float*)d_in[8];
    const float* W_t2  = (const float*)d_in[9];
    const float* a_t2  = (const float*)d_in[10];
    const float* Wm1   = (const float*)d_in[11];
    const float* bm1   = (const float*)d_in[12];
    const float* Wm2   = (const float*)d_in[13];
    const float* bm2   = (const float*)d_in[14];
    float* out = (float*)d_out;

    float* ws = (float*)d_ws;
    float* B_pack  = ws;                        // 512*256*24   = 3,145,728 f32 (12.6 MB)
    float* B_pack2 = B_pack + 512 * 256 * 24;   // 1024*128*16  = 2,097,152 f32 ( 8.4 MB)
    float* Ht_f    = B_pack2 + 1024 * 128 * 16; // 256*128*4*16 = 2,097,152 f32 ( 8.4 MB)

    k1_l1t   <<<dim3(N_DIM, H_DIM, 2), 64, 0, stream>>>(graph, adj_t, W_t1, a_t1, B_pack);
    k2_l1s_ht<<<dim3(T_DIM, H_DIM, 4), 64, 0, stream>>>(adj_s, B_pack, W_s1, a_s1, W_t2, a_t2,
                                                        B_pack2, Ht_f);
    k3_hs_mlp<<<dim3(N_DIM, H_DIM, 2), 64, 0, stream>>>(adj_t, B_pack2, W_s2, a_s2, Ht_f,
                                                        Wm1, bm1, Wm2, bm2, out);
}